// Round 4
// baseline (329.860 us; speedup 1.0000x reference)
//
#include <hip/hip_runtime.h>
#include <hip/hip_bf16.h>

// Problem: B=128, N=196, C=768, centers=64
//   q = mean_n x; attn = softmax(l2n(q)@l2n(k_c) * C^-0.5)
//   v = attn@v_c (B,N,N); out = (v @ x) @ W^T + b
// R7: reassociated to CUT FLOPs (64.5G -> 45.1G) and revert to the proven R4
//   2-phase GEMM structure (R5/R6 deep pipeline = barrier-bound at 1 block/CU):
//     gemm_A: tmp[b,n,k] = sum_m v_pad[b,n,m] * x_t[b,k,m]   (NT, per-batch,
//             M=256, N=768, K=224, BK=32, 16KB LDS)
//     gemm_B: out[(b,n),d] = sum_k tmp[b,n,k] * W[d,k] + bias (NT, FLAT:
//             M=128*224=28672, N=768, K=768, BK=64, 32KB LDS, 1344 blocks,
//             row-mapped f32 store b=row/224, n=row%224, store n<196)
//   convert_x now produces x_t[b, k=768, m=224] bf16 (LDS transpose, chunk-XOR
//   swizzled; m in [196,224) zeroed) + COMPLETE per-batch column sums q_sum.

#define NB   128
#define NN   196
#define NC   768
#define NCEN 64
#define MPAD 224   // padded m (inner dim of v@x); 7*32
#define RPAD 256   // padded n rows of v_pad (2x128 tiles)
#define BGRP 32    // batches per mix block

using bf16x8 = __attribute__((ext_vector_type(8))) short;
using f32x4  = __attribute__((ext_vector_type(4))) float;

__device__ __forceinline__ void async_copy16(const void* g, void* l) {
    // width=16: emits global_load_lds_dwordx4. LDS dest = wave-uniform base + lane*16.
    __builtin_amdgcn_global_load_lds((const __attribute__((address_space(1))) void*)g,
                                     (__attribute__((address_space(3))) void*)l, 16, 0, 0);
}

// ---- kernel 1: x -> x_t[b, c(768), m(224)] bf16 (transposed) + q_sum[b, c] ----
// grid (NB, 12): 64 c-rows per block. LDS tile 64x256 shorts, chunk-XOR swizzle
// (chunk' = chunk ^ (row>>3)) so both the scattered bf16 writes and the b128
// row reads are bank-spread (octet-checked: 8 lanes sharing m hit 8 distinct
// 4-bank groups). m in [196,224) stored as zeros (gemm_A pad correctness).
__global__ __launch_bounds__(256)
void convert_x_kernel(const float* __restrict__ x, __hip_bfloat16* __restrict__ x_t,
                      float* __restrict__ q_sum) {
    __shared__ unsigned short lt[64 * 256];   // 32 KB
    __shared__ float qred[32][64];            // 8 KB
    int b = blockIdx.x, cc = blockIdx.y, t = threadIdx.x;
    int c0 = cc * 64;
    int c8 = t & 7;     // c-octet within block (8 c each)
    int ms = t >> 3;    // m-stripe 0..31
    const float* xp = x + (size_t)b * NN * NC + c0 + c8 * 8;
    float s[8] = {};
#pragma unroll
    for (int it = 0; it < 7; ++it) {
        int m = ms + 32 * it;   // covers 0..223 over the block
        union { bf16x8 v; __hip_bfloat16 h[8]; } u;
        u.v = (bf16x8){};
        if (m < NN) {
            float4 v0 = *(const float4*)(xp + (size_t)m * NC);
            float4 v1 = *(const float4*)(xp + (size_t)m * NC + 4);
            u.h[0] = __float2bfloat16(v0.x); s[0] += v0.x;
            u.h[1] = __float2bfloat16(v0.y); s[1] += v0.y;
            u.h[2] = __float2bfloat16(v0.z); s[2] += v0.z;
            u.h[3] = __float2bfloat16(v0.w); s[3] += v0.w;
            u.h[4] = __float2bfloat16(v1.x); s[4] += v1.x;
            u.h[5] = __float2bfloat16(v1.y); s[5] += v1.y;
            u.h[6] = __float2bfloat16(v1.z); s[6] += v1.z;
            u.h[7] = __float2bfloat16(v1.w); s[7] += v1.w;
        }
        int msw = m ^ (c8 << 3);  // XOR chunk index (bits 3..5) by row>>3 (= c8)
#pragma unroll
        for (int j = 0; j < 8; ++j)
            lt[(c8 * 8 + j) * 256 + msw] = ((unsigned short*)&u)[j];
    }
#pragma unroll
    for (int j = 0; j < 8; ++j) qred[ms][c8 * 8 + j] = s[j];
    __syncthreads();
    // write out 64 rows x 28 chunks of 16B
    {
        int r = t >> 2, c4 = t & 3;
        int key = (r >> 3) & 7;
        __hip_bfloat16* xtr = x_t + (size_t)b * NC * MPAD + (size_t)(c0 + r) * MPAD;
#pragma unroll
        for (int ic = 0; ic < 7; ++ic) {
            int ch = c4 + 4 * ic;  // 0..27
            bf16x8 vv = *(const bf16x8*)&lt[r * 256 + ((ch ^ key) << 3)];
            *(bf16x8*)(xtr + ch * 8) = vv;
        }
    }
    if (t < 64) {
        float q = 0.f;
#pragma unroll
        for (int ss = 0; ss < 32; ++ss) q += qred[ss][t];
        q_sum[(size_t)b * NC + c0 + t] = q;
    }
}

// ---------------- kernel 2: proj_w -> bf16 (vectorized) ----------------
__global__ __launch_bounds__(256)
void convert_w_kernel(const float* __restrict__ w, __hip_bfloat16* __restrict__ w_bf) {
    int i = (blockIdx.x * 256 + threadIdx.x) * 8;
    if (i >= NC * NC) return;
    float4 v0 = *(const float4*)(w + i);
    float4 v1 = *(const float4*)(w + i + 4);
    union { bf16x8 v; __hip_bfloat16 h[8]; } u;
    u.h[0] = __float2bfloat16(v0.x);
    u.h[1] = __float2bfloat16(v0.y);
    u.h[2] = __float2bfloat16(v0.z);
    u.h[3] = __float2bfloat16(v0.w);
    u.h[4] = __float2bfloat16(v1.x);
    u.h[5] = __float2bfloat16(v1.y);
    u.h[6] = __float2bfloat16(v1.z);
    u.h[7] = __float2bfloat16(v1.w);
    *(bf16x8*)(w_bf + i) = u.v;
}

// ---------------- kernel 3: attn = softmax(l2n(q) @ l2n(k_c) * scale) ----------------
__global__ __launch_bounds__(256)
void attn_kernel(const float* __restrict__ q_sum, const float* __restrict__ k_c,
                 float* __restrict__ attn) {
    const float SCALE = 0.03608439182435161f;  // 768^-0.5
    int b = blockIdx.x, t = threadIdx.x;
    __shared__ float qs[NC];
    __shared__ float red[256];
    __shared__ float pd[4][NCEN];
    __shared__ float pk[4][NCEN];

    for (int i = t; i < NC; i += 256)
        qs[i] = q_sum[(size_t)b * NC + i] * (1.0f / (float)NN);
    __syncthreads();

    float s = 0.f;
    for (int i = t; i < NC; i += 256) { float v = qs[i]; s += v * v; }
    red[t] = s;
    __syncthreads();
    for (int o = 128; o > 0; o >>= 1) {
        if (t < o) red[t] += red[t + o];
        __syncthreads();
    }
    float qn = sqrtf(red[0]);

    int j = t & 63, part = t >> 6;
    float d = 0.f, kk = 0.f;
    int c0 = part * 192;
    for (int c = c0; c < c0 + 192; ++c) {
        float kv = k_c[c * NCEN + j];
        d += kv * qs[c];
        kk += kv * kv;
    }
    pd[part][j] = d;
    pk[part][j] = kk;
    __syncthreads();

    if (t < NCEN) {
        float dot = pd[0][t] + pd[1][t] + pd[2][t] + pd[3][t];
        float kn  = sqrtf(pk[0][t] + pk[1][t] + pk[2][t] + pk[3][t]);
        float lg = dot / (fmaxf(qn, 1e-12f) * fmaxf(kn, 1e-12f)) * SCALE;
        float mx = lg;
        for (int o = 32; o > 0; o >>= 1) mx = fmaxf(mx, __shfl_xor(mx, o, 64));
        float e = expf(lg - mx);
        float sum = e;
        for (int o = 32; o > 0; o >>= 1) sum += __shfl_xor(sum, o, 64);
        attn[b * NCEN + t] = e / sum;
    }
}

// ------- kernel 4: v_pad[b,n,m] = sum_c attn[b,c] v_c[c,n,m]; grid (RPAD, NB/BGRP) -------
__global__ __launch_bounds__(256)
void mix_kernel(const float* __restrict__ attn, const float* __restrict__ v_c,
                __hip_bfloat16* __restrict__ v_pad) {
    int n = blockIdx.x;   // 0..255
    int g = blockIdx.y;   // 0..3
    int m = threadIdx.x;  // 0..255, active < MPAD

    __shared__ float sattn[BGRP][NCEN];
    for (int i = threadIdx.x; i < BGRP * NCEN; i += 256)
        sattn[i >> 6][i & 63] = attn[(g * BGRP + (i >> 6)) * NCEN + (i & 63)];
    __syncthreads();

    if (m >= MPAD) return;
    __hip_bfloat16 z = __float2bfloat16(0.f);
    size_t base = (size_t)n * MPAD + m;
    if (n >= NN || m >= NN) {
#pragma unroll
        for (int bb = 0; bb < BGRP; ++bb)
            v_pad[(size_t)(g * BGRP + bb) * RPAD * MPAD + base] = z;
        return;
    }
    float vc[NCEN];
    const float* vp = v_c + (size_t)n * NN + m;
#pragma unroll
    for (int c = 0; c < NCEN; ++c) vc[c] = vp[(size_t)c * NN * NN];
#pragma unroll
    for (int bb = 0; bb < BGRP; ++bb) {
        float acc = 0.f;
#pragma unroll
        for (int c = 0; c < NCEN; ++c) acc += sattn[bb][c] * vc[c];
        v_pad[(size_t)(g * BGRP + bb) * RPAD * MPAD + base] = __float2bfloat16(acc);
    }
}

// ---------------- NT GEMM: C[row,col] = sum_k A[row,k] * B[col,k] ----------------
// R4-proven 2-phase structure: 128x128 tile, 4 waves x (4x4) mfma_f32_16x16x32_bf16,
// global_load_lds width=16, 2-3+ blocks/CU (16/32KB LDS) for cross-block TLP.
// BK=64: fetch-side XOR swizzle (row&7); BK=32: row-parity splits banks, no swizzle.
// 1D grid, XCD-grouped: consecutive w share bm (A-strip L2 reuse); for batched use
// (strideA>0) MPG consecutive w form one batch on one XCD.
// OUTMODE 1: bf16 store at row<Mstore (gemm_A).
// OUTMODE 0: f32 row-mapped store: b=row/224, n=row%224, store n<196 with +bias (gemm_B).
template <int BK, int OUTMODE, int NBM, int NBN>
__global__ __launch_bounds__(256)
void gemm_nt(const __hip_bfloat16* __restrict__ A, size_t strideA,
             const __hip_bfloat16* __restrict__ Bm, size_t strideB,
             void* __restrict__ Cout, size_t strideC,
             const float* __restrict__ bias,
             int lda, int ldb, int ldc, int K, int Mstore) {
    constexpr int MPG = NBM * NBN;
    int L = blockIdx.x;
    int w = (L & 7) * ((int)gridDim.x >> 3) + (L >> 3);
    int bb = w / MPG;
    int i5 = w - bb * MPG;
    int bm = i5 / NBN, bn = i5 % NBN;

    const unsigned short* Ab = (const unsigned short*)A + (size_t)bb * strideA + (size_t)bm * 128 * lda;
    const unsigned short* Bb = (const unsigned short*)Bm + (size_t)bb * strideB + (size_t)bn * 128 * ldb;

    __shared__ __align__(16) unsigned short sA[128 * BK];
    __shared__ __align__(16) unsigned short sB[128 * BK];

    int tid = threadIdx.x;
    int wave = tid >> 6, lane = tid & 63;
    int wr = wave >> 1, wc = wave & 1;
    int lrow = lane & 15, quad = lane >> 4;

    constexpr int CH  = BK / 8;   // 16B chunks per row (8 @ BK64, 4 @ BK32)
    constexpr int RPI = 64 / CH;  // rows per instruction
    constexpr int NI  = 32 / RPI; // instructions per tile per wave
    int srow = lane / CH;
    int sc   = lane % CH;
    int lc   = (BK == 64) ? (sc ^ (srow & 7)) : sc;

    const unsigned short* ga[NI];
    const unsigned short* gb[NI];
    unsigned short* la[NI];
    unsigned short* lb[NI];
#pragma unroll
    for (int i = 0; i < NI; ++i) {
        int row = wave * 32 + i * RPI + srow;
        ga[i] = Ab + (size_t)row * lda + lc * 8;
        gb[i] = Bb + (size_t)row * ldb + lc * 8;
        la[i] = &sA[(wave * 32 + i * RPI) * BK];
        lb[i] = &sB[(wave * 32 + i * RPI) * BK];
    }

    f32x4 acc[4][4] = {};

    for (int k0 = 0; k0 < K; k0 += BK) {
        __syncthreads();
#pragma unroll
        for (int i = 0; i < NI; ++i) async_copy16(ga[i] + k0, la[i]);
#pragma unroll
        for (int i = 0; i < NI; ++i) async_copy16(gb[i] + k0, lb[i]);
        __syncthreads();

#pragma unroll
        for (int kh = 0; kh < BK / 32; ++kh) {
            int pcbase = (BK == 64) ? ((kh * 4 + quad) ^ (lrow & 7)) : quad;
            bf16x8 af[4], bfr[4];
#pragma unroll
            for (int i = 0; i < 4; ++i)
                af[i] = *(const bf16x8*)(&sA[(wr * 64 + i * 16 + lrow) * BK + pcbase * 8]);
#pragma unroll
            for (int j = 0; j < 4; ++j)
                bfr[j] = *(const bf16x8*)(&sB[(wc * 64 + j * 16 + lrow) * BK + pcbase * 8]);
#pragma unroll
            for (int i = 0; i < 4; ++i)
#pragma unroll
                for (int j = 0; j < 4; ++j)
                    acc[i][j] = __builtin_amdgcn_mfma_f32_16x16x32_bf16(af[i], bfr[j], acc[i][j], 0, 0, 0);
        }
    }

    // epilogue: D[row=(lane>>4)*4+r][col=lane&15] per 16x16 tile (m89-verified mapping)
    size_t cbase = (size_t)bb * strideC;
#pragma unroll
    for (int i = 0; i < 4; ++i) {
        int row0 = bm * 128 + wr * 64 + i * 16 + quad * 4;
#pragma unroll
        for (int j = 0; j < 4; ++j) {
            int col = bn * 128 + wc * 64 + j * 16 + lrow;
            float badd = (OUTMODE == 0 && bias) ? bias[col] : 0.f;
#pragma unroll
            for (int r2 = 0; r2 < 4; ++r2) {
                int row = row0 + r2;
                if (OUTMODE == 1) {
                    if (row < Mstore) {
                        ((__hip_bfloat16*)Cout)[cbase + (size_t)row * ldc + col] =
                            __float2bfloat16(acc[i][j][r2]);
                    }
                } else {
                    int b2 = row / MPAD;
                    int n  = row - b2 * MPAD;
                    if (n < NN) {
                        ((float*)Cout)[((size_t)b2 * NN + n) * ldc + col] =
                            acc[i][j][r2] + badd;
                    }
                }
            }
        }
    }
}

extern "C" void kernel_launch(void* const* d_in, const int* in_sizes, int n_in,
                              void* d_out, int out_size, void* d_ws, size_t ws_size,
                              hipStream_t stream) {
    const float* x      = (const float*)d_in[0];  // (128,196,768)
    const float* k_c    = (const float*)d_in[1];  // (768,64)
    const float* v_c    = (const float*)d_in[2];  // (64,196,196)
    const float* proj_w = (const float*)d_in[3];  // (768,768)
    const float* proj_b = (const float*)d_in[4];  // (768,)
    float* out = (float*)d_out;                   // (128,196,768)

    char* ws = (char*)d_ws;
    size_t off = 0;
    auto alloc = [&](size_t bytes) {
        void* p = ws + off;
        off = (off + bytes + 255) & ~(size_t)255;
        return p;
    };
    __hip_bfloat16* x_t   = (__hip_bfloat16*)alloc((size_t)NB * NC * MPAD * 2);   // 44.0 MB
    __hip_bfloat16* w_bf  = (__hip_bfloat16*)alloc((size_t)NC * NC * 2);          // 1.2 MB
    __hip_bfloat16* tmp   = (__hip_bfloat16*)alloc((size_t)NB * MPAD * NC * 2);   // 44.0 MB
    __hip_bfloat16* v_pad = (__hip_bfloat16*)alloc((size_t)NB * RPAD * MPAD * 2); // 14.7 MB
    float* q_sum = (float*)alloc((size_t)NB * NC * 4);                            // 0.4 MB
    float* attn  = (float*)alloc((size_t)NB * NCEN * 4);

    convert_x_kernel<<<dim3(NB, 12), 256, 0, stream>>>(x, x_t, q_sum);
    convert_w_kernel<<<dim3((NC * NC / 8 + 255) / 256), 256, 0, stream>>>(proj_w, w_bf);
    attn_kernel<<<dim3(NB), 256, 0, stream>>>(q_sum, k_c, attn);
    mix_kernel<<<dim3(RPAD, NB / BGRP), 256, 0, stream>>>(attn, v_c, v_pad);

    // gemm_A: tmp[b,n,k] = sum_m v_pad[b,n,m] * x_t[b,k,m]
    // M=256 (2 tiles, store 224), N=768 (6 tiles), K=224, batched over 128
    gemm_nt<32, 1, 2, 6><<<dim3(2 * 6 * NB), 256, 0, stream>>>(
        v_pad, (size_t)RPAD * MPAD, x_t, (size_t)NC * MPAD, tmp, (size_t)MPAD * NC,
        nullptr, MPAD, MPAD, NC, MPAD, MPAD);

    // gemm_B: out[(b,n),d] = sum_k tmp[b,n,k] * W[d,k] + bias[d]
    // FLAT: M=28672 (224 tiles), N=768 (6 tiles), K=768, row-mapped f32 store
    gemm_nt<64, 0, 224, 6><<<dim3(224 * 6), 256, 0, stream>>>(
        tmp, 0, w_bf, 0, out, 0,
        proj_b, NC, NC, NC, NC, 224 * NB);
}

// Round 5
// 264.812 us; speedup vs baseline: 1.2456x; 1.2456x over previous
//
#include <hip/hip_runtime.h>
#include <hip/hip_bf16.h>

// Problem: B=128, N=196, C=768, centers=64
//   q = mean_n x; attn = softmax(l2n(q)@l2n(k_c) * C^-0.5)
//   v = attn@v_c (B,N,N); out = (v @ x) @ W^T + b
// R8: attn_kernel was the hidden serial bottleneck (~70us, top-5 all attn in R7):
//   192 serial scalar strided k_c loads/thread at 1 wave/SIMD = pure exposed
//   latency. Rewritten: thread (j4, part) does 48 independent float4 loads
//   (unroll 8, ~8 in flight), LDS partial reduce pd[16][64]. Everything else
//   unchanged from R7 (reassociated gemm_A = v@x per batch, flat gemm_B = @W^T).

#define NB   128
#define NN   196
#define NC   768
#define NCEN 64
#define MPAD 224   // padded m (inner dim of v@x); 7*32
#define RPAD 256   // padded n rows of v_pad (2x128 tiles)
#define BGRP 32    // batches per mix block

using bf16x8 = __attribute__((ext_vector_type(8))) short;
using f32x4  = __attribute__((ext_vector_type(4))) float;

__device__ __forceinline__ void async_copy16(const void* g, void* l) {
    // width=16: emits global_load_lds_dwordx4. LDS dest = wave-uniform base + lane*16.
    __builtin_amdgcn_global_load_lds((const __attribute__((address_space(1))) void*)g,
                                     (__attribute__((address_space(3))) void*)l, 16, 0, 0);
}

// ---- kernel 1: x -> x_t[b, c(768), m(224)] bf16 (transposed) + q_sum[b, c] ----
// grid (NB, 12): 64 c-rows per block. LDS tile 64x256 shorts, chunk-XOR swizzle
// (chunk' = chunk ^ (row>>3)) so both the scattered bf16 writes and the b128
// row reads are bank-spread. m in [196,224) stored as zeros (gemm_A pad).
__global__ __launch_bounds__(256)
void convert_x_kernel(const float* __restrict__ x, __hip_bfloat16* __restrict__ x_t,
                      float* __restrict__ q_sum) {
    __shared__ unsigned short lt[64 * 256];   // 32 KB
    __shared__ float qred[32][64];            // 8 KB
    int b = blockIdx.x, cc = blockIdx.y, t = threadIdx.x;
    int c0 = cc * 64;
    int c8 = t & 7;     // c-octet within block (8 c each)
    int ms = t >> 3;    // m-stripe 0..31
    const float* xp = x + (size_t)b * NN * NC + c0 + c8 * 8;
    float s[8] = {};
#pragma unroll
    for (int it = 0; it < 7; ++it) {
        int m = ms + 32 * it;   // covers 0..223 over the block
        union { bf16x8 v; __hip_bfloat16 h[8]; } u;
        u.v = (bf16x8){};
        if (m < NN) {
            float4 v0 = *(const float4*)(xp + (size_t)m * NC);
            float4 v1 = *(const float4*)(xp + (size_t)m * NC + 4);
            u.h[0] = __float2bfloat16(v0.x); s[0] += v0.x;
            u.h[1] = __float2bfloat16(v0.y); s[1] += v0.y;
            u.h[2] = __float2bfloat16(v0.z); s[2] += v0.z;
            u.h[3] = __float2bfloat16(v0.w); s[3] += v0.w;
            u.h[4] = __float2bfloat16(v1.x); s[4] += v1.x;
            u.h[5] = __float2bfloat16(v1.y); s[5] += v1.y;
            u.h[6] = __float2bfloat16(v1.z); s[6] += v1.z;
            u.h[7] = __float2bfloat16(v1.w); s[7] += v1.w;
        }
        int msw = m ^ (c8 << 3);  // XOR chunk index (bits 3..5) by row>>3 (= c8)
#pragma unroll
        for (int j = 0; j < 8; ++j)
            lt[(c8 * 8 + j) * 256 + msw] = ((unsigned short*)&u)[j];
    }
#pragma unroll
    for (int j = 0; j < 8; ++j) qred[ms][c8 * 8 + j] = s[j];
    __syncthreads();
    // write out 64 rows x 28 chunks of 16B
    {
        int r = t >> 2, c4 = t & 3;
        int key = (r >> 3) & 7;
        __hip_bfloat16* xtr = x_t + (size_t)b * NC * MPAD + (size_t)(c0 + r) * MPAD;
#pragma unroll
        for (int ic = 0; ic < 7; ++ic) {
            int ch = c4 + 4 * ic;  // 0..27
            bf16x8 vv = *(const bf16x8*)&lt[r * 256 + ((ch ^ key) << 3)];
            *(bf16x8*)(xtr + ch * 8) = vv;
        }
    }
    if (t < 64) {
        float q = 0.f;
#pragma unroll
        for (int ss = 0; ss < 32; ++ss) q += qred[ss][t];
        q_sum[(size_t)b * NC + c0 + t] = q;
    }
}

// ---------------- kernel 2: proj_w -> bf16 (vectorized) ----------------
__global__ __launch_bounds__(256)
void convert_w_kernel(const float* __restrict__ w, __hip_bfloat16* __restrict__ w_bf) {
    int i = (blockIdx.x * 256 + threadIdx.x) * 8;
    if (i >= NC * NC) return;
    float4 v0 = *(const float4*)(w + i);
    float4 v1 = *(const float4*)(w + i + 4);
    union { bf16x8 v; __hip_bfloat16 h[8]; } u;
    u.h[0] = __float2bfloat16(v0.x);
    u.h[1] = __float2bfloat16(v0.y);
    u.h[2] = __float2bfloat16(v0.z);
    u.h[3] = __float2bfloat16(v0.w);
    u.h[4] = __float2bfloat16(v1.x);
    u.h[5] = __float2bfloat16(v1.y);
    u.h[6] = __float2bfloat16(v1.z);
    u.h[7] = __float2bfloat16(v1.w);
    *(bf16x8*)(w_bf + i) = u.v;
}

// ---------------- kernel 3: attn = softmax(l2n(q) @ l2n(k_c) * scale) ----------------
// R8: ILP rewrite. Thread (j4 = (t&15)*4, part = t>>4) accumulates 48 c's with
// float4 loads over j (k_c row-major [c][64], 16B-aligned); unroll 8 keeps ~8
// independent loads in flight (was: 192 serial scalar strided loads = ~70us of
// exposed latency at 1 wave/SIMD). LDS partial reduce pd/pk[16][64].
__global__ __launch_bounds__(256)
void attn_kernel(const float* __restrict__ q_sum, const float* __restrict__ k_c,
                 float* __restrict__ attn) {
    const float SCALE = 0.03608439182435161f;  // 768^-0.5
    int b = blockIdx.x, t = threadIdx.x;
    __shared__ float qs[NC];
    __shared__ float red[256];
    __shared__ float pd[16][NCEN];
    __shared__ float pk[16][NCEN];

    for (int i = t; i < NC; i += 256)
        qs[i] = q_sum[(size_t)b * NC + i] * (1.0f / (float)NN);
    __syncthreads();

    float s = 0.f;
    for (int i = t; i < NC; i += 256) { float v = qs[i]; s += v * v; }
    red[t] = s;
    __syncthreads();
    for (int o = 128; o > 0; o >>= 1) {
        if (t < o) red[t] += red[t + o];
        __syncthreads();
    }
    float qn = sqrtf(red[0]);

    int j4 = (t & 15) * 4;   // j base (16 groups of 4)
    int part = t >> 4;       // 16 parts x 48 c's
    const float* kp = k_c + j4;
    float d0 = 0.f, d1 = 0.f, d2 = 0.f, d3 = 0.f;
    float e0 = 0.f, e1 = 0.f, e2 = 0.f, e3 = 0.f;
    int c0 = part * 48;
#pragma unroll 8
    for (int c = c0; c < c0 + 48; ++c) {
        float4 kv = *(const float4*)(kp + (size_t)c * NCEN);
        float qv = qs[c];
        d0 += qv * kv.x; d1 += qv * kv.y; d2 += qv * kv.z; d3 += qv * kv.w;
        e0 += kv.x * kv.x; e1 += kv.y * kv.y; e2 += kv.z * kv.z; e3 += kv.w * kv.w;
    }
    pd[part][j4 + 0] = d0; pd[part][j4 + 1] = d1; pd[part][j4 + 2] = d2; pd[part][j4 + 3] = d3;
    pk[part][j4 + 0] = e0; pk[part][j4 + 1] = e1; pk[part][j4 + 2] = e2; pk[part][j4 + 3] = e3;
    __syncthreads();

    if (t < NCEN) {
        float dot = 0.f, kk = 0.f;
#pragma unroll
        for (int p = 0; p < 16; ++p) { dot += pd[p][t]; kk += pk[p][t]; }
        float kn = sqrtf(kk);
        float lg = dot / (fmaxf(qn, 1e-12f) * fmaxf(kn, 1e-12f)) * SCALE;
        float mx = lg;
        for (int o = 32; o > 0; o >>= 1) mx = fmaxf(mx, __shfl_xor(mx, o, 64));
        float e = expf(lg - mx);
        float sum = e;
        for (int o = 32; o > 0; o >>= 1) sum += __shfl_xor(sum, o, 64);
        attn[b * NCEN + t] = e / sum;
    }
}

// ------- kernel 4: v_pad[b,n,m] = sum_c attn[b,c] v_c[c,n,m]; grid (RPAD, NB/BGRP) -------
__global__ __launch_bounds__(256)
void mix_kernel(const float* __restrict__ attn, const float* __restrict__ v_c,
                __hip_bfloat16* __restrict__ v_pad) {
    int n = blockIdx.x;   // 0..255
    int g = blockIdx.y;   // 0..3
    int m = threadIdx.x;  // 0..255, active < MPAD

    __shared__ float sattn[BGRP][NCEN];
    for (int i = threadIdx.x; i < BGRP * NCEN; i += 256)
        sattn[i >> 6][i & 63] = attn[(g * BGRP + (i >> 6)) * NCEN + (i & 63)];
    __syncthreads();

    if (m >= MPAD) return;
    __hip_bfloat16 z = __float2bfloat16(0.f);
    size_t base = (size_t)n * MPAD + m;
    if (n >= NN || m >= NN) {
#pragma unroll
        for (int bb = 0; bb < BGRP; ++bb)
            v_pad[(size_t)(g * BGRP + bb) * RPAD * MPAD + base] = z;
        return;
    }
    float vc[NCEN];
    const float* vp = v_c + (size_t)n * NN + m;
#pragma unroll
    for (int c = 0; c < NCEN; ++c) vc[c] = vp[(size_t)c * NN * NN];
#pragma unroll
    for (int bb = 0; bb < BGRP; ++bb) {
        float acc = 0.f;
#pragma unroll
        for (int c = 0; c < NCEN; ++c) acc += sattn[bb][c] * vc[c];
        v_pad[(size_t)(g * BGRP + bb) * RPAD * MPAD + base] = __float2bfloat16(acc);
    }
}

// ---------------- NT GEMM: C[row,col] = sum_k A[row,k] * B[col,k] ----------------
// R4-proven 2-phase structure: 128x128 tile, 4 waves x (4x4) mfma_f32_16x16x32_bf16,
// global_load_lds width=16, 2-3+ blocks/CU (16/32KB LDS) for cross-block TLP.
// BK=64: fetch-side XOR swizzle (row&7); BK=32: row-parity splits banks, no swizzle.
// OUTMODE 1: bf16 store at row<Mstore (gemm_A).
// OUTMODE 0: f32 row-mapped store: b=row/224, n=row%224, store n<196 with +bias (gemm_B).
template <int BK, int OUTMODE, int NBM, int NBN>
__global__ __launch_bounds__(256)
void gemm_nt(const __hip_bfloat16* __restrict__ A, size_t strideA,
             const __hip_bfloat16* __restrict__ Bm, size_t strideB,
             void* __restrict__ Cout, size_t strideC,
             const float* __restrict__ bias,
             int lda, int ldb, int ldc, int K, int Mstore) {
    constexpr int MPG = NBM * NBN;
    int L = blockIdx.x;
    int w = (L & 7) * ((int)gridDim.x >> 3) + (L >> 3);
    int bb = w / MPG;
    int i5 = w - bb * MPG;
    int bm = i5 / NBN, bn = i5 % NBN;

    const unsigned short* Ab = (const unsigned short*)A + (size_t)bb * strideA + (size_t)bm * 128 * lda;
    const unsigned short* Bb = (const unsigned short*)Bm + (size_t)bb * strideB + (size_t)bn * 128 * ldb;

    __shared__ __align__(16) unsigned short sA[128 * BK];
    __shared__ __align__(16) unsigned short sB[128 * BK];

    int tid = threadIdx.x;
    int wave = tid >> 6, lane = tid & 63;
    int wr = wave >> 1, wc = wave & 1;
    int lrow = lane & 15, quad = lane >> 4;

    constexpr int CH  = BK / 8;   // 16B chunks per row (8 @ BK64, 4 @ BK32)
    constexpr int RPI = 64 / CH;  // rows per instruction
    constexpr int NI  = 32 / RPI; // instructions per tile per wave
    int srow = lane / CH;
    int sc   = lane % CH;
    int lc   = (BK == 64) ? (sc ^ (srow & 7)) : sc;

    const unsigned short* ga[NI];
    const unsigned short* gb[NI];
    unsigned short* la[NI];
    unsigned short* lb[NI];
#pragma unroll
    for (int i = 0; i < NI; ++i) {
        int row = wave * 32 + i * RPI + srow;
        ga[i] = Ab + (size_t)row * lda + lc * 8;
        gb[i] = Bb + (size_t)row * ldb + lc * 8;
        la[i] = &sA[(wave * 32 + i * RPI) * BK];
        lb[i] = &sB[(wave * 32 + i * RPI) * BK];
    }

    f32x4 acc[4][4] = {};

    for (int k0 = 0; k0 < K; k0 += BK) {
        __syncthreads();
#pragma unroll
        for (int i = 0; i < NI; ++i) async_copy16(ga[i] + k0, la[i]);
#pragma unroll
        for (int i = 0; i < NI; ++i) async_copy16(gb[i] + k0, lb[i]);
        __syncthreads();

#pragma unroll
        for (int kh = 0; kh < BK / 32; ++kh) {
            int pcbase = (BK == 64) ? ((kh * 4 + quad) ^ (lrow & 7)) : quad;
            bf16x8 af[4], bfr[4];
#pragma unroll
            for (int i = 0; i < 4; ++i)
                af[i] = *(const bf16x8*)(&sA[(wr * 64 + i * 16 + lrow) * BK + pcbase * 8]);
#pragma unroll
            for (int j = 0; j < 4; ++j)
                bfr[j] = *(const bf16x8*)(&sB[(wc * 64 + j * 16 + lrow) * BK + pcbase * 8]);
#pragma unroll
            for (int i = 0; i < 4; ++i)
#pragma unroll
                for (int j = 0; j < 4; ++j)
                    acc[i][j] = __builtin_amdgcn_mfma_f32_16x16x32_bf16(af[i], bfr[j], acc[i][j], 0, 0, 0);
        }
    }

    // epilogue: D[row=(lane>>4)*4+r][col=lane&15] per 16x16 tile (m89-verified mapping)
    size_t cbase = (size_t)bb * strideC;
#pragma unroll
    for (int i = 0; i < 4; ++i) {
        int row0 = bm * 128 + wr * 64 + i * 16 + quad * 4;
#pragma unroll
        for (int j = 0; j < 4; ++j) {
            int col = bn * 128 + wc * 64 + j * 16 + lrow;
            float badd = (OUTMODE == 0 && bias) ? bias[col] : 0.f;
#pragma unroll
            for (int r2 = 0; r2 < 4; ++r2) {
                int row = row0 + r2;
                if (OUTMODE == 1) {
                    if (row < Mstore) {
                        ((__hip_bfloat16*)Cout)[cbase + (size_t)row * ldc + col] =
                            __float2bfloat16(acc[i][j][r2]);
                    }
                } else {
                    int b2 = row / MPAD;
                    int n  = row - b2 * MPAD;
                    if (n < NN) {
                        ((float*)Cout)[((size_t)b2 * NN + n) * ldc + col] =
                            acc[i][j][r2] + badd;
                    }
                }
            }
        }
    }
}

extern "C" void kernel_launch(void* const* d_in, const int* in_sizes, int n_in,
                              void* d_out, int out_size, void* d_ws, size_t ws_size,
                              hipStream_t stream) {
    const float* x      = (const float*)d_in[0];  // (128,196,768)
    const float* k_c    = (const float*)d_in[1];  // (768,64)
    const float* v_c    = (const float*)d_in[2];  // (64,196,196)
    const float* proj_w = (const float*)d_in[3];  // (768,768)
    const float* proj_b = (const float*)d_in[4];  // (768,)
    float* out = (float*)d_out;                   // (128,196,768)

    char* ws = (char*)d_ws;
    size_t off = 0;
    auto alloc = [&](size_t bytes) {
        void* p = ws + off;
        off = (off + bytes + 255) & ~(size_t)255;
        return p;
    };
    __hip_bfloat16* x_t   = (__hip_bfloat16*)alloc((size_t)NB * NC * MPAD * 2);   // 44.0 MB
    __hip_bfloat16* w_bf  = (__hip_bfloat16*)alloc((size_t)NC * NC * 2);          // 1.2 MB
    __hip_bfloat16* tmp   = (__hip_bfloat16*)alloc((size_t)NB * MPAD * NC * 2);   // 44.0 MB
    __hip_bfloat16* v_pad = (__hip_bfloat16*)alloc((size_t)NB * RPAD * MPAD * 2); // 14.7 MB
    float* q_sum = (float*)alloc((size_t)NB * NC * 4);                            // 0.4 MB
    float* attn  = (float*)alloc((size_t)NB * NCEN * 4);

    convert_x_kernel<<<dim3(NB, 12), 256, 0, stream>>>(x, x_t, q_sum);
    convert_w_kernel<<<dim3((NC * NC / 8 + 255) / 256), 256, 0, stream>>>(proj_w, w_bf);
    attn_kernel<<<dim3(NB), 256, 0, stream>>>(q_sum, k_c, attn);
    mix_kernel<<<dim3(RPAD, NB / BGRP), 256, 0, stream>>>(attn, v_c, v_pad);

    // gemm_A: tmp[b,n,k] = sum_m v_pad[b,n,m] * x_t[b,k,m]
    // M=256 (2 tiles, store 224), N=768 (6 tiles), K=224, batched over 128
    gemm_nt<32, 1, 2, 6><<<dim3(2 * 6 * NB), 256, 0, stream>>>(
        v_pad, (size_t)RPAD * MPAD, x_t, (size_t)NC * MPAD, tmp, (size_t)MPAD * NC,
        nullptr, MPAD, MPAD, NC, MPAD, MPAD);

    // gemm_B: out[(b,n),d] = sum_k tmp[b,n,k] * W[d,k] + bias[d]
    // FLAT: M=28672 (224 tiles), N=768 (6 tiles), K=768, row-mapped f32 store
    gemm_nt<64, 0, 224, 6><<<dim3(224 * 6), 256, 0, stream>>>(
        tmp, 0, w_bf, 0, out, 0,
        proj_b, NC, NC, NC, NC, 224 * NB);
}